// Round 1
// baseline (448.883 us; speedup 1.0000x reference)
//
#include <hip/hip_runtime.h>

#define T 512          // threads per block
#define EPT 32         // elements per thread (16384 / 512)
#define ROWLEN 16384
#define BINS1 4096
#define NW (T / 64)    // waves per block
#define EQCAP 512

// Order-preserving float->uint transform: u(a) < u(b)  <=>  a < b
__device__ __forceinline__ unsigned f2ord(float f) {
    unsigned b = __float_as_uint(f);
    return b ^ ((b & 0x80000000u) ? 0xFFFFFFFFu : 0x80000000u);
}
__device__ __forceinline__ float ord2f(unsigned u) {
    unsigned b = (u & 0x80000000u) ? (u ^ 0x80000000u) : ~u;
    return __uint_as_float(b);
}

// Block-cooperative: given hist[0..BINS), find bin b* = max{b : S(b) >= k},
// S(b) = sum_{d>=b} hist[d]. Writes *sh_b = b*, *sh_k = k - S(b*+1).
// Ends with __syncthreads().
__device__ __forceinline__ void select_bin(const int* hist, int BINS, int k,
                                           int* waveSum, int* sh_b, int* sh_k) {
    const int tid  = threadIdx.x;
    const int lane = tid & 63;
    const int w    = tid >> 6;

    int bpt = (BINS + T - 1) / T;
    int lo  = tid * bpt; if (lo > BINS) lo = BINS;
    int hi  = lo + bpt;  if (hi > BINS) hi = BINS;

    int p = 0;
    for (int d = lo; d < hi; ++d) p += hist[d];

    // inclusive suffix scan within wave (64 lanes)
    int v = p;
    #pragma unroll
    for (int off = 1; off < 64; off <<= 1) {
        int t2 = __shfl_down(v, off);
        if (lane + off < 64) v += t2;
    }
    if (lane == 0) waveSum[w] = v;   // wave total
    __syncthreads();

    int carry = 0;
    for (int w2 = w + 1; w2 < NW; ++w2) carry += waveSum[w2];

    int P  = v + carry;   // S(lo)
    int Pn = P - p;       // S(hi)
    if (P >= k && Pn < k) {          // unique thread: crossing is in [lo,hi)
        int running = Pn;
        for (int d = hi - 1; d >= lo; --d) {
            running += hist[d];
            if (running >= k) {
                *sh_b = d;
                *sh_k = k - (running - hist[d]);   // still needed inside bin d
                break;
            }
        }
    }
    __syncthreads();
}

__global__ __launch_bounds__(T, 4) void topk_relu_scatter(
        const float* __restrict__ x, const int* __restrict__ kptr,
        float* __restrict__ out) {
    __shared__ int hist[BINS1];
    __shared__ int waveSum[NW];
    __shared__ int sh_b, sh_k;
    __shared__ int sh_idxcut;
    __shared__ int eqCount;
    __shared__ int eqIdx[EQCAP];

    const int tid = threadIdx.x;
    const int row = blockIdx.x;
    const float4* xrow = (const float4*)(x + (size_t)row * ROWLEN);
    float4*       orow = (float4*)(out + (size_t)row * ROWLEN);

    // ---- single global read: 8 x float4 per thread, coalesced ----
    unsigned u[EPT];
    #pragma unroll
    for (int j4 = 0; j4 < EPT / 4; ++j4) {
        float4 v = xrow[tid + T * j4];
        u[4 * j4 + 0] = f2ord(v.x);
        u[4 * j4 + 1] = f2ord(v.y);
        u[4 * j4 + 2] = f2ord(v.z);
        u[4 * j4 + 3] = f2ord(v.w);
    }

    int k = *kptr;   // k = 128 (device scalar, uniform)

    // ---- pass 1: top 12 bits ----
    for (int i = tid; i < BINS1; i += T) hist[i] = 0;
    __syncthreads();
    #pragma unroll
    for (int j = 0; j < EPT; ++j) atomicAdd(&hist[u[j] >> 20], 1);
    __syncthreads();
    select_bin(hist, 4096, k, waveSum, &sh_b, &sh_k);
    unsigned b1 = (unsigned)sh_b; k = sh_k;

    // ---- pass 2: middle 12 bits among prefix-matched ----
    for (int i = tid; i < BINS1; i += T) hist[i] = 0;
    __syncthreads();
    #pragma unroll
    for (int j = 0; j < EPT; ++j)
        if ((u[j] >> 20) == b1) atomicAdd(&hist[(u[j] >> 8) & 0xFFFu], 1);
    __syncthreads();
    select_bin(hist, 4096, k, waveSum, &sh_b, &sh_k);
    unsigned pref2 = (b1 << 12) | (unsigned)sh_b; k = sh_k;

    // ---- pass 3: low 8 bits among prefix-matched ----
    for (int i = tid; i < BINS1; i += T) hist[i] = 0;
    __syncthreads();
    #pragma unroll
    for (int j = 0; j < EPT; ++j)
        if ((u[j] >> 8) == pref2) atomicAdd(&hist[u[j] & 0xFFu], 1);
    __syncthreads();
    select_bin(hist, 256, k, waveSum, &sh_b, &sh_k);
    const unsigned ustar = (pref2 << 8) | (unsigned)sh_b;
    const int t_eq = sh_k;   // how many elements == ustar to accept (lowest idx first)

    // ---- resolve tie cut: t_eq-th smallest index among equals ----
    if (tid == 0) eqCount = 0;
    __syncthreads();
    #pragma unroll
    for (int j = 0; j < EPT; ++j) {
        if (u[j] == ustar) {
            int pos = atomicAdd(&eqCount, 1);
            if (pos < EQCAP) {
                int idx = 4 * (tid + T * (j >> 2)) + (j & 3);
                eqIdx[pos] = idx;
            }
        }
    }
    __syncthreads();
    if (tid == 0) {
        int m = eqCount; if (m > EQCAP) m = EQCAP;
        int cut;
        if (t_eq >= m) {
            cut = ROWLEN;                 // accept all equals
        } else {
            cut = -1;                     // t_eq-th smallest via repeated min-extract
            for (int it = 0; it < t_eq; ++it) {
                int mn = 0x7FFFFFFF, mi = -1;
                for (int i = 0; i < m; ++i)
                    if (eqIdx[i] < mn) { mn = eqIdx[i]; mi = i; }
                cut = mn; eqIdx[mi] = 0x7FFFFFFF;
            }
        }
        sh_idxcut = cut;
    }
    __syncthreads();
    const int idxcut = sh_idxcut;

    // ---- single global write: decode regs, ReLU, dense store ----
    #pragma unroll
    for (int j4 = 0; j4 < EPT / 4; ++j4) {
        float4 o;
        float* op = &o.x;
        #pragma unroll
        for (int c = 0; c < 4; ++c) {
            unsigned uu = u[4 * j4 + c];
            int idx = 4 * (tid + T * j4) + c;
            bool sel = (uu > ustar) || (uu == ustar && idx <= idxcut);
            float xv = ord2f(uu);
            op[c] = (sel && xv > 0.0f) ? xv : 0.0f;
        }
        orow[tid + T * j4] = o;
    }
}

extern "C" void kernel_launch(void* const* d_in, const int* in_sizes, int n_in,
                              void* d_out, int out_size, void* d_ws, size_t ws_size,
                              hipStream_t stream) {
    const float* x    = (const float*)d_in[0];
    const int*   kptr = (const int*)d_in[1];
    float*       out  = (float*)d_out;
    int rows = in_sizes[0] / ROWLEN;   // 4096
    topk_relu_scatter<<<rows, T, 0, stream>>>(x, kptr, out);
}